// Round 1
// baseline (343.450 us; speedup 1.0000x reference)
//
#include <hip/hip_runtime.h>
#include <stdint.h>

// ---------------------------------------------------------------------------
// CausalSelfAttention fused pipeline for MI355X (gfx950)
//   B=4, T=2048, C=1024, H=16, hd=64
//   x[B,T,C] f32, w_qkv[C,3C] f32, w_proj[C,C] f32 -> out[B,T,C] f32
// Pipeline: cast/transposes -> GEMM1(qkv, scatter per-head) -> V transpose
//           -> flash attention (bf16 MFMA, online softmax, swizzled LDS)
//           -> GEMM2(out proj, fp32 output)
// Workspace: 72 MB (assumed <= ws_size), deterministic, fully rewritten/call.
// ---------------------------------------------------------------------------

typedef __bf16 bf16x8 __attribute__((ext_vector_type(8)));
typedef float f32x4 __attribute__((ext_vector_type(4)));
typedef unsigned short u16x8 __attribute__((ext_vector_type(8)));

#define DEVINL static __device__ __forceinline__

DEVINL unsigned short f2b(float f) {
  __bf16 h = (__bf16)f;           // RNE
  return __builtin_bit_cast(unsigned short, h);
}

DEVINL void gld16(const void* g, void* l) {
  __builtin_amdgcn_global_load_lds(
      (const __attribute__((address_space(1))) void*)g,
      (__attribute__((address_space(3))) void*)l, 16, 0, 0);
}

DEVINL f32x4 mfma16(bf16x8 a, bf16x8 b, f32x4 c) {
  return __builtin_amdgcn_mfma_f32_16x16x32_bf16(a, b, c, 0, 0, 0);
}

// ---------------------------------------------------------------- cast x->bf16
__global__ __launch_bounds__(256) void k_cast_bf16(const float* __restrict__ in,
                                                   unsigned short* __restrict__ out,
                                                   int n8) {
  int i = blockIdx.x * 256 + threadIdx.x;
  if (i >= n8) return;
  const float4* p = (const float4*)in + (size_t)i * 2;
  float4 a = p[0], b = p[1];
  u16x8 o;
  o[0] = f2b(a.x); o[1] = f2b(a.y); o[2] = f2b(a.z); o[3] = f2b(a.w);
  o[4] = f2b(b.x); o[5] = f2b(b.y); o[6] = f2b(b.z); o[7] = f2b(b.w);
  *(u16x8*)(out + (size_t)i * 8) = o;
}

// ------------------------------------------- W [R][C] f32 -> Wt [C][R] bf16
__global__ __launch_bounds__(256) void k_transpose_w(const float* __restrict__ in,
                                                     unsigned short* __restrict__ out,
                                                     int R, int C) {
  __shared__ float t[64][65];
  int ci = blockIdx.x * 64, ri = blockIdx.y * 64;
  int tid = threadIdx.x;
#pragma unroll
  for (int j = 0; j < 4; ++j) {
    int c = tid + j * 256;           // 0..1023 float4 chunks of the 64x64 tile
    int row = c >> 4;
    int col = (c & 15) * 4;
    float4 v = *(const float4*)(in + (size_t)(ri + row) * C + ci + col);
    t[row][col] = v.x; t[row][col + 1] = v.y; t[row][col + 2] = v.z; t[row][col + 3] = v.w;
  }
  __syncthreads();
  int cc = tid >> 2;                 // output row (C index), 0..63
  int seg = (tid & 3) * 16;
  u16x8 o0, o1;
#pragma unroll
  for (int j = 0; j < 8; ++j) o0[j] = f2b(t[seg + j][cc]);
#pragma unroll
  for (int j = 0; j < 8; ++j) o1[j] = f2b(t[seg + 8 + j][cc]);
  unsigned short* dst = out + (size_t)(ci + cc) * R + ri + seg;
  *(u16x8*)dst = o0;
  *(u16x8*)(dst + 8) = o1;
}

// --------------------------------- V [bh][2048][64] -> Vt [bh][64][2048] bf16
__global__ __launch_bounds__(256) void k_transpose_v(const unsigned short* __restrict__ v,
                                                     unsigned short* __restrict__ vt) {
  __shared__ unsigned short s[64][65];
  int bh = blockIdx.y;
  int t0 = blockIdx.x * 64;
  int tid = threadIdx.x;
  const unsigned short* src = v + ((size_t)bh * 2048 + t0) * 64;
#pragma unroll
  for (int j = 0; j < 2; ++j) {
    int c = tid + j * 256;           // 0..511 (16B chunks of 64x64 bf16 tile)
    int row = c >> 3;
    int col = (c & 7) * 8;
    u16x8 x = *(const u16x8*)(src + (size_t)row * 64 + col);
#pragma unroll
    for (int q = 0; q < 8; ++q) s[row][col + q] = x[q];
  }
  __syncthreads();
  int d = tid >> 2;                  // 0..63
  int seg = (tid & 3) * 16;
  u16x8 o0, o1;
#pragma unroll
  for (int j = 0; j < 8; ++j) o0[j] = s[seg + j][d];
#pragma unroll
  for (int j = 0; j < 8; ++j) o1[j] = s[seg + 8 + j][d];
  unsigned short* dst = vt + ((size_t)bh * 64 + d) * 2048 + t0 + seg;
  *(u16x8*)dst = o0;
  *(u16x8*)(dst + 8) = o1;
}

// ---------------------------------------------------------------- GEMM (A Bt)
// A [M][K] bf16, Bt [N][K] bf16. 128x128 tile, BK=32, 4 waves (2x2 of 64x64).
// MODE 0: scatter into q/k/v per-head layout (q scaled). MODE 1: fp32 C out.
template <int MODE>
__global__ __launch_bounds__(256) void k_gemm(const unsigned short* __restrict__ A,
                                              const unsigned short* __restrict__ Bt,
                                              int M, int N, int K,
                                              float* __restrict__ Cf,
                                              unsigned short* __restrict__ qo,
                                              unsigned short* __restrict__ ko,
                                              unsigned short* __restrict__ vo,
                                              float qscale) {
  __shared__ unsigned short As[128 * 32];   // 8 KB
  __shared__ unsigned short Bs[128 * 32];   // 8 KB
  int tid = threadIdx.x;
  int w = tid >> 6, lane = tid & 63, l15 = lane & 15, l4 = lane >> 4;
  int bn = blockIdx.x, bm = blockIdx.y;
  int wr = (w >> 1) * 64, wc = (w & 1) * 64;
  f32x4 acc[4][4];
#pragma unroll
  for (int i = 0; i < 4; ++i)
#pragma unroll
    for (int j = 0; j < 4; ++j) acc[i][j] = (f32x4){0.f, 0.f, 0.f, 0.f};
  const char* Ab = (const char*)(A + (size_t)bm * 128 * K);
  const char* Bb = (const char*)(Bt + (size_t)bn * 128 * K);
  for (int kt = 0; kt < K; kt += 32) {
#pragma unroll
    for (int c0 = 0; c0 < 2; ++c0) {
      int c = tid + c0 * 256;            // 0..511: 16B chunk of [128][32] tile
      int row = c >> 2, cb = (c & 3) * 16;
      gld16(Ab + ((size_t)row * K + kt) * 2 + cb, (char*)As + c * 16);
      gld16(Bb + ((size_t)row * K + kt) * 2 + cb, (char*)Bs + c * 16);
    }
    __syncthreads();
    bf16x8 af[4], bfr[4];
#pragma unroll
    for (int m = 0; m < 4; ++m)
      af[m] = *(const bf16x8*)((const char*)As + (wr + m * 16 + l15) * 64 + l4 * 16);
#pragma unroll
    for (int n = 0; n < 4; ++n)
      bfr[n] = *(const bf16x8*)((const char*)Bs + (wc + n * 16 + l15) * 64 + l4 * 16);
#pragma unroll
    for (int m = 0; m < 4; ++m)
#pragma unroll
      for (int n = 0; n < 4; ++n)
        acc[m][n] = mfma16(af[m], bfr[n], acc[m][n]);
    __syncthreads();
  }
  // epilogue: D col = lane&15, row = (lane>>4)*4 + reg  [m89-verified]
#pragma unroll
  for (int m = 0; m < 4; ++m) {
    int grow0 = bm * 128 + wr + m * 16 + l4 * 4;
#pragma unroll
    for (int n = 0; n < 4; ++n) {
      int gcol = bn * 128 + wc + n * 16 + l15;
#pragma unroll
      for (int r = 0; r < 4; ++r) {
        int grow = grow0 + r;
        float val = acc[m][n][r];
        if (MODE == 1) {
          Cf[(size_t)grow * N + gcol] = val;
        } else {
          int which = gcol >> 10, rem = gcol & 1023;
          int h = rem >> 6, d = rem & 63;
          int b = grow >> 11, t = grow & 2047;
          size_t off = (((size_t)(b * 16 + h)) * 2048 + t) * 64 + d;
          if (which == 0)      qo[off] = f2b(val * qscale);
          else if (which == 1) ko[off] = f2b(val);
          else                 vo[off] = f2b(val);
        }
      }
    }
  }
}

// ------------------------------------------------------------ flash attention
// Q,K: [bh][2048][64] bf16 (Q pre-scaled by 0.125*log2e); Vt: [bh][64][2048].
// Block: 4 waves, 64 q-rows (16/wave), KV tile 64. LDS K/Vt/P XOR-swizzled:
//   swz(x) = x ^ (((x>>7)&7)<<4)  (involution; rows at 128B stride)
__global__ __launch_bounds__(256) void k_attn(const unsigned short* __restrict__ Q,
                                              const unsigned short* __restrict__ Kt,
                                              const unsigned short* __restrict__ Vt,
                                              unsigned short* __restrict__ AO) {
  __shared__ unsigned short Ks[4096];   // 8 KB  [64 kv][64 d]
  __shared__ unsigned short Vs[4096];   // 8 KB  [64 d][64 kv]
  __shared__ unsigned short Ps[4096];   // 8 KB  4 waves x [16 q][64 kv]
  int tid = threadIdx.x;
  int w = tid >> 6, lane = tid & 63, l15 = lane & 15, l4 = lane >> 4;
  int bh = blockIdx.y;
  int qi = gridDim.x - 1 - blockIdx.x;   // heavy tiles launch first
  int q0 = qi * 64;
  const char* Kb = (const char*)(Kt + (size_t)bh * 2048 * 64);
  const char* Vb = (const char*)(Vt + (size_t)bh * 64 * 2048);
  const unsigned short* Qb = Q + ((size_t)bh * 2048 + q0 + w * 16) * 64;
  bf16x8 qf[2];
  qf[0] = *(const bf16x8*)((const char*)Qb + l15 * 128 + l4 * 16);
  qf[1] = *(const bf16x8*)((const char*)Qb + l15 * 128 + 64 + l4 * 16);
  f32x4 o[4];
#pragma unroll
  for (int i = 0; i < 4; ++i) o[i] = (f32x4){0.f, 0.f, 0.f, 0.f};
  float mrow[4] = {-1e30f, -1e30f, -1e30f, -1e30f};
  float lrow[4] = {0.f, 0.f, 0.f, 0.f};
  int ntiles = qi + 1;
  for (int it = 0; it < ntiles; ++it) {
    int kv0 = it * 64;
#pragma unroll
    for (int j = 0; j < 2; ++j) {
      int Lb = ((w + j * 4) * 64 + lane) * 16;       // linear LDS byte
      int Nb = Lb ^ (((Lb >> 7) & 7) << 4);          // pre-swizzled source byte
      gld16(Kb + (size_t)kv0 * 128 + Nb, (char*)Ks + Lb);
      int d = Nb >> 7, inner = Nb & 127;
      gld16(Vb + (size_t)d * 4096 + kv0 * 2 + inner, (char*)Vs + Lb);
    }
    __syncthreads();
    // S = Q K^T (log2 domain; scale folded into Q)
    f32x4 s[4];
#pragma unroll
    for (int c = 0; c < 4; ++c) {
      int row = c * 16 + l15;
      int base = row * 128 + l4 * 16;
      int sw = (row & 7) << 4;
      bf16x8 k0 = *(const bf16x8*)((const char*)Ks + (base ^ sw));
      bf16x8 k1 = *(const bf16x8*)((const char*)Ks + ((base + 64) ^ sw));
      f32x4 t = mfma16(qf[0], k0, (f32x4){0.f, 0.f, 0.f, 0.f});
      s[c] = mfma16(qf[1], k1, t);
    }
    if (kv0 == q0) {   // diagonal tile: causal mask
#pragma unroll
      for (int c = 0; c < 4; ++c) {
        int kvr = c * 16 + l15;
#pragma unroll
        for (int r = 0; r < 4; ++r)
          if (kvr > w * 16 + l4 * 4 + r) s[c][r] = -1e30f;
      }
    }
    float mx[4];
#pragma unroll
    for (int r = 0; r < 4; ++r) {
      float m0 = fmaxf(fmaxf(s[0][r], s[1][r]), fmaxf(s[2][r], s[3][r]));
      m0 = fmaxf(m0, __shfl_xor(m0, 1));
      m0 = fmaxf(m0, __shfl_xor(m0, 2));
      m0 = fmaxf(m0, __shfl_xor(m0, 4));
      m0 = fmaxf(m0, __shfl_xor(m0, 8));
      mx[r] = m0;
    }
    float corr[4], rs[4];
#pragma unroll
    for (int r = 0; r < 4; ++r) {
      float mn = fmaxf(mrow[r], mx[r]);
      corr[r] = exp2f(mrow[r] - mn);
      mrow[r] = mn;
      rs[r] = 0.f;
    }
    char* Pw = (char*)Ps + w * 2048;
#pragma unroll
    for (int c = 0; c < 4; ++c) {
#pragma unroll
      for (int r = 0; r < 4; ++r) {
        float p = exp2f(s[c][r] - mrow[r]);
        rs[r] += p;
        int qrow = l4 * 4 + r;
        int nat = qrow * 128 + (c * 16 + l15) * 2;
        *(unsigned short*)(Pw + (nat ^ ((qrow & 7) << 4))) = f2b(p);
      }
    }
#pragma unroll
    for (int r = 0; r < 4; ++r) {
      float t = rs[r];
      t += __shfl_xor(t, 1); t += __shfl_xor(t, 2);
      t += __shfl_xor(t, 4); t += __shfl_xor(t, 8);
      lrow[r] = lrow[r] * corr[r] + t;
    }
#pragma unroll
    for (int dc = 0; dc < 4; ++dc)
#pragma unroll
      for (int r = 0; r < 4; ++r) o[dc][r] *= corr[r];
    // O += P V   (P from this wave's LDS region; Vs swizzled)
#pragma unroll
    for (int dc = 0; dc < 4; ++dc) {
#pragma unroll
      for (int kc = 0; kc < 2; ++kc) {
        int pnat = l15 * 128 + kc * 64 + l4 * 16;
        bf16x8 pa = *(const bf16x8*)(Pw + (pnat ^ ((l15 & 7) << 4)));
        int vrow = dc * 16 + l15;
        int vnat = vrow * 128 + kc * 64 + l4 * 16;
        bf16x8 vb = *(const bf16x8*)((const char*)Vs + (vnat ^ ((vrow & 7) << 4)));
        o[dc] = mfma16(pa, vb, o[dc]);
      }
    }
    __syncthreads();
  }
  int b = bh >> 4, h = bh & 15;
  float inv[4];
#pragma unroll
  for (int r = 0; r < 4; ++r) inv[r] = 1.f / lrow[r];
#pragma unroll
  for (int dc = 0; dc < 4; ++dc) {
#pragma unroll
    for (int r = 0; r < 4; ++r) {
      int t = q0 + w * 16 + l4 * 4 + r;
      AO[((size_t)(b * 2048 + t)) * 1024 + h * 64 + dc * 16 + l15] =
          f2b(o[dc][r] * inv[r]);
    }
  }
}

// ---------------------------------------------------------------------------
extern "C" void kernel_launch(void* const* d_in, const int* in_sizes, int n_in,
                              void* d_out, int out_size, void* d_ws, size_t ws_size,
                              hipStream_t stream) {
  const float* x      = (const float*)d_in[0];   // [4,2048,1024]
  const float* w_qkv  = (const float*)d_in[1];   // [1024,3072]
  const float* w_proj = (const float*)d_in[2];   // [1024,1024]
  float* out = (float*)d_out;                    // [4,2048,1024] f32
  char* ws = (char*)d_ws;
  const size_t MB = 1024 * 1024;
  // xb and vT alias (vT written after GEMM1 consumed xb); ao aliases v.
  unsigned short* xb     = (unsigned short*)(ws);            // 16MB [8192][1024]
  unsigned short* vT     = (unsigned short*)(ws);            // 16MB [64][64][2048]
  unsigned short* wqkvT  = (unsigned short*)(ws + 16 * MB);  // 6MB [3072][1024]
  unsigned short* wprojT = (unsigned short*)(ws + 22 * MB);  // 2MB [1024][1024]
  unsigned short* q      = (unsigned short*)(ws + 24 * MB);  // 16MB [64][2048][64]
  unsigned short* k      = (unsigned short*)(ws + 40 * MB);  // 16MB
  unsigned short* v      = (unsigned short*)(ws + 56 * MB);  // 16MB
  unsigned short* ao     = (unsigned short*)(ws + 56 * MB);  // 16MB [8192][1024]

  k_cast_bf16<<<4096, 256, 0, stream>>>(x, xb, 1048576);
  k_transpose_w<<<dim3(48, 16), 256, 0, stream>>>(w_qkv, wqkvT, 1024, 3072);
  k_transpose_w<<<dim3(16, 16), 256, 0, stream>>>(w_proj, wprojT, 1024, 1024);
  const float qscale = 0.125f * 1.44269504088896f;  // hd^-0.5 * log2(e)
  k_gemm<0><<<dim3(24, 64), 256, 0, stream>>>(xb, wqkvT, 8192, 3072, 1024,
                                              nullptr, q, k, v, qscale);
  k_transpose_v<<<dim3(32, 64), 256, 0, stream>>>(v, vT);
  k_attn<<<dim3(32, 64), 256, 0, stream>>>(q, k, vT, ao);
  k_gemm<1><<<dim3(8, 64), 256, 0, stream>>>(ao, wprojT, 8192, 1024, 1024,
                                             out, nullptr, nullptr, nullptr, 1.f);
}

// Round 2
// 291.918 us; speedup vs baseline: 1.1765x; 1.1765x over previous
//
#include <hip/hip_runtime.h>
#include <stdint.h>

// ---------------------------------------------------------------------------
// CausalSelfAttention fused pipeline for MI355X (gfx950)
//   B=4, T=2048, C=1024, H=16, hd=64
// Round 2: k_attn rewritten — swapped QK^T (S^T layout, lane-local softmax),
//          packed b64 P writes, double-buffered K/V LDS, 1 barrier/tile.
// ---------------------------------------------------------------------------

typedef __bf16 bf16x8 __attribute__((ext_vector_type(8)));
typedef float f32x4 __attribute__((ext_vector_type(4)));
typedef unsigned short u16x8 __attribute__((ext_vector_type(8)));

#define DEVINL static __device__ __forceinline__

DEVINL unsigned short f2b(float f) {
  __bf16 h = (__bf16)f;           // RNE
  return __builtin_bit_cast(unsigned short, h);
}

DEVINL void gld16(const void* g, void* l) {
  __builtin_amdgcn_global_load_lds(
      (const __attribute__((address_space(1))) void*)g,
      (__attribute__((address_space(3))) void*)l, 16, 0, 0);
}

DEVINL f32x4 mfma16(bf16x8 a, bf16x8 b, f32x4 c) {
  return __builtin_amdgcn_mfma_f32_16x16x32_bf16(a, b, c, 0, 0, 0);
}

// ---------------------------------------------------------------- cast x->bf16
__global__ __launch_bounds__(256) void k_cast_bf16(const float* __restrict__ in,
                                                   unsigned short* __restrict__ out,
                                                   int n8) {
  int i = blockIdx.x * 256 + threadIdx.x;
  if (i >= n8) return;
  const float4* p = (const float4*)in + (size_t)i * 2;
  float4 a = p[0], b = p[1];
  u16x8 o;
  o[0] = f2b(a.x); o[1] = f2b(a.y); o[2] = f2b(a.z); o[3] = f2b(a.w);
  o[4] = f2b(b.x); o[5] = f2b(b.y); o[6] = f2b(b.z); o[7] = f2b(b.w);
  *(u16x8*)(out + (size_t)i * 8) = o;
}

// ------------------------------------------- W [R][C] f32 -> Wt [C][R] bf16
__global__ __launch_bounds__(256) void k_transpose_w(const float* __restrict__ in,
                                                     unsigned short* __restrict__ out,
                                                     int R, int C) {
  __shared__ float t[64][65];
  int ci = blockIdx.x * 64, ri = blockIdx.y * 64;
  int tid = threadIdx.x;
#pragma unroll
  for (int j = 0; j < 4; ++j) {
    int c = tid + j * 256;           // 0..1023 float4 chunks of the 64x64 tile
    int row = c >> 4;
    int col = (c & 15) * 4;
    float4 v = *(const float4*)(in + (size_t)(ri + row) * C + ci + col);
    t[row][col] = v.x; t[row][col + 1] = v.y; t[row][col + 2] = v.z; t[row][col + 3] = v.w;
  }
  __syncthreads();
  int cc = tid >> 2;                 // output row (C index), 0..63
  int seg = (tid & 3) * 16;
  u16x8 o0, o1;
#pragma unroll
  for (int j = 0; j < 8; ++j) o0[j] = f2b(t[seg + j][cc]);
#pragma unroll
  for (int j = 0; j < 8; ++j) o1[j] = f2b(t[seg + 8 + j][cc]);
  unsigned short* dst = out + (size_t)(ci + cc) * R + ri + seg;
  *(u16x8*)dst = o0;
  *(u16x8*)(dst + 8) = o1;
}

// --------------------------------- V [bh][2048][64] -> Vt [bh][64][2048] bf16
__global__ __launch_bounds__(256) void k_transpose_v(const unsigned short* __restrict__ v,
                                                     unsigned short* __restrict__ vt) {
  __shared__ unsigned short s[64][65];
  int bh = blockIdx.y;
  int t0 = blockIdx.x * 64;
  int tid = threadIdx.x;
  const unsigned short* src = v + ((size_t)bh * 2048 + t0) * 64;
#pragma unroll
  for (int j = 0; j < 2; ++j) {
    int c = tid + j * 256;           // 0..511 (16B chunks of 64x64 bf16 tile)
    int row = c >> 3;
    int col = (c & 7) * 8;
    u16x8 x = *(const u16x8*)(src + (size_t)row * 64 + col);
#pragma unroll
    for (int q = 0; q < 8; ++q) s[row][col + q] = x[q];
  }
  __syncthreads();
  int d = tid >> 2;                  // 0..63
  int seg = (tid & 3) * 16;
  u16x8 o0, o1;
#pragma unroll
  for (int j = 0; j < 8; ++j) o0[j] = s[seg + j][d];
#pragma unroll
  for (int j = 0; j < 8; ++j) o1[j] = s[seg + 8 + j][d];
  unsigned short* dst = vt + ((size_t)bh * 64 + d) * 2048 + t0 + seg;
  *(u16x8*)dst = o0;
  *(u16x8*)(dst + 8) = o1;
}

// ---------------------------------------------------------------- GEMM (A Bt)
// A [M][K] bf16, Bt [N][K] bf16. 128x128 tile, BK=32, 4 waves (2x2 of 64x64).
// MODE 0: scatter into q/k/v per-head layout (q scaled). MODE 1: fp32 C out.
template <int MODE>
__global__ __launch_bounds__(256) void k_gemm(const unsigned short* __restrict__ A,
                                              const unsigned short* __restrict__ Bt,
                                              int M, int N, int K,
                                              float* __restrict__ Cf,
                                              unsigned short* __restrict__ qo,
                                              unsigned short* __restrict__ ko,
                                              unsigned short* __restrict__ vo,
                                              float qscale) {
  __shared__ unsigned short As[128 * 32];   // 8 KB
  __shared__ unsigned short Bs[128 * 32];   // 8 KB
  int tid = threadIdx.x;
  int w = tid >> 6, lane = tid & 63, l15 = lane & 15, l4 = lane >> 4;
  int bn = blockIdx.x, bm = blockIdx.y;
  int wr = (w >> 1) * 64, wc = (w & 1) * 64;
  f32x4 acc[4][4];
#pragma unroll
  for (int i = 0; i < 4; ++i)
#pragma unroll
    for (int j = 0; j < 4; ++j) acc[i][j] = (f32x4){0.f, 0.f, 0.f, 0.f};
  const char* Ab = (const char*)(A + (size_t)bm * 128 * K);
  const char* Bb = (const char*)(Bt + (size_t)bn * 128 * K);
  for (int kt = 0; kt < K; kt += 32) {
#pragma unroll
    for (int c0 = 0; c0 < 2; ++c0) {
      int c = tid + c0 * 256;            // 0..511: 16B chunk of [128][32] tile
      int row = c >> 2, cb = (c & 3) * 16;
      gld16(Ab + ((size_t)row * K + kt) * 2 + cb, (char*)As + c * 16);
      gld16(Bb + ((size_t)row * K + kt) * 2 + cb, (char*)Bs + c * 16);
    }
    __syncthreads();
    bf16x8 af[4], bfr[4];
#pragma unroll
    for (int m = 0; m < 4; ++m)
      af[m] = *(const bf16x8*)((const char*)As + (wr + m * 16 + l15) * 64 + l4 * 16);
#pragma unroll
    for (int n = 0; n < 4; ++n)
      bfr[n] = *(const bf16x8*)((const char*)Bs + (wc + n * 16 + l15) * 64 + l4 * 16);
#pragma unroll
    for (int m = 0; m < 4; ++m)
#pragma unroll
      for (int n = 0; n < 4; ++n)
        acc[m][n] = mfma16(af[m], bfr[n], acc[m][n]);
    __syncthreads();
  }
  // epilogue: D col = lane&15, row = (lane>>4)*4 + reg  [m89-verified]
#pragma unroll
  for (int m = 0; m < 4; ++m) {
    int grow0 = bm * 128 + wr + m * 16 + l4 * 4;
#pragma unroll
    for (int n = 0; n < 4; ++n) {
      int gcol = bn * 128 + wc + n * 16 + l15;
#pragma unroll
      for (int r = 0; r < 4; ++r) {
        int grow = grow0 + r;
        float val = acc[m][n][r];
        if (MODE == 1) {
          Cf[(size_t)grow * N + gcol] = val;
        } else {
          int which = gcol >> 10, rem = gcol & 1023;
          int h = rem >> 6, d = rem & 63;
          int b = grow >> 11, t = grow & 2047;
          size_t off = (((size_t)(b * 16 + h)) * 2048 + t) * 64 + d;
          if (which == 0)      qo[off] = f2b(val * qscale);
          else if (which == 1) ko[off] = f2b(val);
          else                 vo[off] = f2b(val);
        }
      }
    }
  }
}

// ------------------------------------------------------------ flash attention
// Q,K: [bh][2048][64] bf16 (Q pre-scaled by 0.125*log2e); Vt: [bh][64][2048].
// 4 waves x 16 q-rows (QBLK=64), KVBLK=64, K/V double-buffered in LDS.
// Swapped QK^T: S^T = mfma(K,Q) -> lane holds 16 kv scores for q = lane&15.
// LDS XOR swizzle: byte ^ ((row&7)<<4), rows at 128B stride.
__global__ __launch_bounds__(256) void k_attn(const unsigned short* __restrict__ Q,
                                              const unsigned short* __restrict__ Kt,
                                              const unsigned short* __restrict__ Vt,
                                              unsigned short* __restrict__ AO) {
  __shared__ unsigned short Ks[2][4096];   // 16 KB  [64 kv][64 d]
  __shared__ unsigned short Vs[2][4096];   // 16 KB  [64 d][64 kv]
  __shared__ unsigned short Ps[4096];      //  8 KB  4 waves x [16 q][64 kv]
  int tid = threadIdx.x;
  int w = tid >> 6, lane = tid & 63, l15 = lane & 15, l4 = lane >> 4;
  int bh = blockIdx.y;
  int qi = gridDim.x - 1 - blockIdx.x;   // heavy tiles launch first
  int q0 = qi * 64;
  const char* Kb = (const char*)(Kt + (size_t)bh * 2048 * 64);
  const char* Vb = (const char*)(Vt + (size_t)bh * 64 * 2048);
  const unsigned short* Qb = Q + ((size_t)bh * 2048 + q0 + w * 16) * 64;
  bf16x8 qf[2];
  qf[0] = *(const bf16x8*)((const char*)Qb + l15 * 128 + l4 * 16);
  qf[1] = *(const bf16x8*)((const char*)Qb + l15 * 128 + 64 + l4 * 16);
  f32x4 o[4];
#pragma unroll
  for (int i = 0; i < 4; ++i) o[i] = (f32x4){0.f, 0.f, 0.f, 0.f};
  float mrow = -1e30f, lrow = 0.f;       // per-lane state for q = l15
  int ntiles = qi + 1;
  // stage tile 0 into buffer 0
  {
#pragma unroll
    for (int j = 0; j < 2; ++j) {
      int Lb = ((w + j * 4) * 64 + lane) * 16;
      int Nb = Lb ^ (((Lb >> 7) & 7) << 4);
      gld16(Kb + Nb, (char*)Ks[0] + Lb);
      int d = Nb >> 7, inner = Nb & 127;
      gld16(Vb + (size_t)d * 4096 + inner, (char*)Vs[0] + Lb);
    }
  }
  __syncthreads();
  const int swp = (l15 & 7) << 4;        // P-row swizzle for this lane
  char* Pw = (char*)Ps + w * 2048;
  for (int it = 0; it < ntiles; ++it) {
    int cur = it & 1;
    if (it + 1 < ntiles) {               // stage next tile into other buffer
      int kv0n = (it + 1) * 64;
#pragma unroll
      for (int j = 0; j < 2; ++j) {
        int Lb = ((w + j * 4) * 64 + lane) * 16;
        int Nb = Lb ^ (((Lb >> 7) & 7) << 4);
        gld16(Kb + (size_t)kv0n * 128 + Nb, (char*)Ks[cur ^ 1] + Lb);
        int d = Nb >> 7, inner = Nb & 127;
        gld16(Vb + (size_t)d * 4096 + kv0n * 2 + inner, (char*)Vs[cur ^ 1] + Lb);
      }
    }
    const char* Kc = (const char*)Ks[cur];
    const char* Vc = (const char*)Vs[cur];
    // S^T = K Q^T: lane holds s[c][r] = S[q = l15][kv = c*16 + l4*4 + r]
    f32x4 s[4];
#pragma unroll
    for (int c = 0; c < 4; ++c) {
      int row = c * 16 + l15;
      int base = row * 128 + l4 * 16;
      int sw = (row & 7) << 4;
      bf16x8 k0 = *(const bf16x8*)(Kc + (base ^ sw));
      bf16x8 k1 = *(const bf16x8*)(Kc + ((base + 64) ^ sw));
      f32x4 t = mfma16(k0, qf[0], (f32x4){0.f, 0.f, 0.f, 0.f});
      s[c] = mfma16(k1, qf[1], t);
    }
    if (it == ntiles - 1) {              // diagonal tile: causal mask
      int qg = w * 16 + l15;
#pragma unroll
      for (int c = 0; c < 4; ++c) {
        int kvb = c * 16 + l4 * 4;
#pragma unroll
        for (int r = 0; r < 4; ++r)
          if (kvb + r > qg) s[c][r] = -1e30f;
      }
    }
    // lane-local row max over 16 + reduce across l4 group (2 shuffles)
    float mx = fmaxf(fmaxf(fmaxf(s[0][0], s[0][1]), fmaxf(s[0][2], s[0][3])),
                     fmaxf(fmaxf(s[1][0], s[1][1]), fmaxf(s[1][2], s[1][3])));
    mx = fmaxf(mx, fmaxf(fmaxf(fmaxf(s[2][0], s[2][1]), fmaxf(s[2][2], s[2][3])),
                         fmaxf(fmaxf(s[3][0], s[3][1]), fmaxf(s[3][2], s[3][3]))));
    mx = fmaxf(mx, __shfl_xor(mx, 16));
    mx = fmaxf(mx, __shfl_xor(mx, 32));
    float mn = fmaxf(mrow, mx);
    float corr = exp2f(mrow - mn);
    mrow = mn;
    float rs = 0.f;
#pragma unroll
    for (int c = 0; c < 4; ++c) {
      float p0 = exp2f(s[c][0] - mn), p1 = exp2f(s[c][1] - mn);
      float p2 = exp2f(s[c][2] - mn), p3 = exp2f(s[c][3] - mn);
      rs += (p0 + p1) + (p2 + p3);
      uint32_t lo = (uint32_t)f2b(p0) | ((uint32_t)f2b(p1) << 16);
      uint32_t hi = (uint32_t)f2b(p2) | ((uint32_t)f2b(p3) << 16);
      *(uint2*)(Pw + ((l15 * 128 + c * 32 + l4 * 8) ^ swp)) = make_uint2(lo, hi);
    }
    rs += __shfl_xor(rs, 16);
    rs += __shfl_xor(rs, 32);
    lrow = lrow * corr + rs;
    // broadcast corr from l15-layout to o's row layout (q = l4*4 + r)
    float corr_r[4];
#pragma unroll
    for (int r = 0; r < 4; ++r) corr_r[r] = __shfl(corr, l4 * 4 + r);
#pragma unroll
    for (int dc = 0; dc < 4; ++dc)
#pragma unroll
      for (int r = 0; r < 4; ++r) o[dc][r] *= corr_r[r];
    // O += P V  (P A-frag: row = l15 = q, chunk l4; V^T rows = d)
    bf16x8 pa[2];
#pragma unroll
    for (int kc = 0; kc < 2; ++kc)
      pa[kc] = *(const bf16x8*)(Pw + ((l15 * 128 + kc * 64 + l4 * 16) ^ swp));
#pragma unroll
    for (int dc = 0; dc < 4; ++dc) {
#pragma unroll
      for (int kc = 0; kc < 2; ++kc) {
        int vrow = dc * 16 + l15;
        int vnat = vrow * 128 + kc * 64 + l4 * 16;
        bf16x8 vb = *(const bf16x8*)(Vc + (vnat ^ ((vrow & 7) << 4)));
        o[dc] = mfma16(pa[kc], vb, o[dc]);
      }
    }
    __syncthreads();
  }
  int b = bh >> 4, h = bh & 15;
  float inv[4];
#pragma unroll
  for (int r = 0; r < 4; ++r) inv[r] = 1.f / __shfl(lrow, l4 * 4 + r);
#pragma unroll
  for (int dc = 0; dc < 4; ++dc) {
#pragma unroll
    for (int r = 0; r < 4; ++r) {
      int t = q0 + w * 16 + l4 * 4 + r;
      AO[((size_t)(b * 2048 + t)) * 1024 + h * 64 + dc * 16 + l15] =
          f2b(o[dc][r] * inv[r]);
    }
  }
}

// ---------------------------------------------------------------------------
extern "C" void kernel_launch(void* const* d_in, const int* in_sizes, int n_in,
                              void* d_out, int out_size, void* d_ws, size_t ws_size,
                              hipStream_t stream) {
  const float* x      = (const float*)d_in[0];   // [4,2048,1024]
  const float* w_qkv  = (const float*)d_in[1];   // [1024,3072]
  const float* w_proj = (const float*)d_in[2];   // [1024,1024]
  float* out = (float*)d_out;                    // [4,2048,1024] f32
  char* ws = (char*)d_ws;
  const size_t MB = 1024 * 1024;
  // xb and vT alias (vT written after GEMM1 consumed xb); ao aliases v.
  unsigned short* xb     = (unsigned short*)(ws);            // 16MB [8192][1024]
  unsigned short* vT     = (unsigned short*)(ws);            // 16MB [64][64][2048]
  unsigned short* wqkvT  = (unsigned short*)(ws + 16 * MB);  // 6MB [3072][1024]
  unsigned short* wprojT = (unsigned short*)(ws + 22 * MB);  // 2MB [1024][1024]
  unsigned short* q      = (unsigned short*)(ws + 24 * MB);  // 16MB [64][2048][64]
  unsigned short* k      = (unsigned short*)(ws + 40 * MB);  // 16MB
  unsigned short* v      = (unsigned short*)(ws + 56 * MB);  // 16MB
  unsigned short* ao     = (unsigned short*)(ws + 56 * MB);  // 16MB [8192][1024]

  k_cast_bf16<<<4096, 256, 0, stream>>>(x, xb, 1048576);
  k_transpose_w<<<dim3(48, 16), 256, 0, stream>>>(w_qkv, wqkvT, 1024, 3072);
  k_transpose_w<<<dim3(16, 16), 256, 0, stream>>>(w_proj, wprojT, 1024, 1024);
  const float qscale = 0.125f * 1.44269504088896f;  // hd^-0.5 * log2(e)
  k_gemm<0><<<dim3(24, 64), 256, 0, stream>>>(xb, wqkvT, 8192, 3072, 1024,
                                              nullptr, q, k, v, qscale);
  k_transpose_v<<<dim3(32, 64), 256, 0, stream>>>(v, vT);
  k_attn<<<dim3(32, 64), 256, 0, stream>>>(q, k, vT, ao);
  k_gemm<1><<<dim3(8, 64), 256, 0, stream>>>(ao, wprojT, 8192, 1024, 1024,
                                             out, nullptr, nullptr, nullptr, 1.f);
}